// Round 19
// baseline (437.707 us; speedup 1.0000x reference)
//
#include <hip/hip_runtime.h>
#include <hip/hip_bf16.h>
#include <cstdint>

#define B_ 64
#define S_ 2048
#define D_ 512
#define H_ 512

typedef short s16x8 __attribute__((ext_vector_type(8)));
typedef float f32x4 __attribute__((ext_vector_type(4)));

static __device__ __forceinline__ unsigned short f2bf(float f) {
  __bf16 h = (__bf16)f;
  return __builtin_bit_cast(unsigned short, h);
}

// ---------------- fused prep: detect (128) + W-pack (128) + inp (256 blk) ----
// Also zeroes the done[64]/done2[64] counters used by the fused tails
// (runs first in every launch/replay -> re-poison safe).
__global__ __launch_bounds__(256) void k_prep(
    const unsigned int* __restrict__ mw, int* __restrict__ flags,
    int* __restrict__ done, int* __restrict__ done2,
    const float* __restrict__ W, unsigned short* __restrict__ Wp,
    const float* __restrict__ x, const float* __restrict__ W_in,
    const float* __restrict__ b_in, const float* __restrict__ b_ctx,
    float* __restrict__ inp_pb) {
  const int bx = blockIdx.x;
  const int t = threadIdx.x;
  if (bx < 128) {
    __shared__ int blk;
    if (t == 0) blk = 0;
    if (t == 128) {
      if (bx < 64) done[bx] = 0;
      else done2[bx - 64] = 0;
    }
    __syncthreads();
    unsigned w = mw[bx * 256 + t];
    int bits = 0;
    if (w == 0x3F800000u) bits = 2;
    else if (w > 1u) bits = 1;
    unsigned long long a1 = __ballot(bits & 1);
    unsigned long long a2 = __ballot(bits & 2);
    if ((t & 63) == 0) {
      int v = (a1 ? 1 : 0) | (a2 ? 2 : 0);
      if (v) atomicOr(&blk, v);
    }
    __syncthreads();
    if (t == 0) flags[bx] = blk;
  } else if (bx < 256) {
    // pack W_ctx -> fragment-major bf16
    const int tid = (bx - 128) * 256 + t;
    const int lane = tid & 63;
    const int hb = (tid >> 6) & 31;
    const int kb = tid >> 11;
    const int h = hb * 16 + (lane & 15);
    const int k = kb * 32 + (lane >> 4) * 8;
    const float* src = W + (size_t)h * D_ + k;
    float4 a = *(const float4*)src;
    float4 c = *(const float4*)(src + 4);
    s16x8 o;
    o[0] = (short)f2bf(a.x); o[1] = (short)f2bf(a.y);
    o[2] = (short)f2bf(a.z); o[3] = (short)f2bf(a.w);
    o[4] = (short)f2bf(c.x); o[5] = (short)f2bf(c.y);
    o[6] = (short)f2bf(c.z); o[7] = (short)f2bf(c.w);
    *(s16x8*)(Wp + (size_t)tid * 8) = o;
  } else {
    // inp' = x @ W_in^T + b_in + b_ctx : 256 blocks = (b, h-quarter)
    const int bb = bx - 256;
    const int b = bb >> 2, hq = bb & 3;
    __shared__ float xs[D_];
    xs[t] = x[b * D_ + t];
    xs[t + 256] = x[b * D_ + t + 256];
    __syncthreads();
    const int h = hq * 128 + (t >> 1);
    const int half = t & 1;
    const float4* wr = (const float4*)(W_in + (size_t)h * D_) + half * 64;
    const float* xh = xs + half * 256;
    float acc = 0.f;
#pragma unroll 4
    for (int d4 = 0; d4 < 64; ++d4) {
      float4 w = wr[d4];
      acc += w.x * xh[d4 * 4] + w.y * xh[d4 * 4 + 1] + w.z * xh[d4 * 4 + 2] +
             w.w * xh[d4 * 4 + 3];
    }
    acc += __shfl_xor(acc, 1, 64);
    if (half == 0) inp_pb[b * H_ + h] = acc + b_in[h] + b_ctx[h];
  }
}

// ---------------- att + FUSED masked softmax (last WG of each b) ----------------
// R13 schedule (measured best). After the att-tile store, each WG does a
// device-scope release (threadfence) + atomicAdd(done[b]); the 32nd arriver
// acquires and runs the full-row masked softmax for b (512 thr x 4 vals),
// writing alpha. No spinning -> no deadlock; values order-independent.
__global__ __launch_bounds__(512, 2) void k_att(
    const float* __restrict__ context, const unsigned short* __restrict__ Wp,
    const float* __restrict__ inp_pb, const float* __restrict__ V,
    float* __restrict__ att, const void* __restrict__ mask,
    const int* __restrict__ flags, int* __restrict__ done,
    float* __restrict__ alpha) {
  __shared__ char bt[2][8192];  // [s 64][k 64] bf16, 128B rows, swizzled
  __shared__ float red[8][64];
  const int tid = threadIdx.x;
  const int wave = tid >> 6, lane = tid & 63;
  const int b = blockIdx.y, s0 = blockIdx.x * 64;
  const float* ctxb = context + ((size_t)b * S_ + s0) * D_;
  const int hbase = wave * 64;
  const int bln = lane & 15, blh = lane >> 4;

  const int srow = tid >> 3, kc8 = (tid & 7) * 8;
  const int sbyte = srow * 128 + ((kc8 * 2) ^ ((srow & 7) << 4));
  const float* gsrc = ctxb + (size_t)srow * D_ + kc8;

  const unsigned short* ap = Wp + ((size_t)(wave * 4) * 64 + lane) * 8;

  f32x4 acc[4][4];
#pragma unroll
  for (int m = 0; m < 4; ++m)
#pragma unroll
    for (int n = 0; n < 4; ++n) acc[m][n] = f32x4{0.f, 0.f, 0.f, 0.f};

  // depth-3 staging register sets: set i holds tile x with x%3 == i
  f32x4 sg0a, sg0b, sg1a, sg1b, sg2a, sg2b;
#define LOAD_SET0(T) { sg0a = __builtin_nontemporal_load((const f32x4*)(gsrc + (T)*64)); \
                       sg0b = __builtin_nontemporal_load((const f32x4*)(gsrc + (T)*64 + 4)); }
#define LOAD_SET1(T) { sg1a = __builtin_nontemporal_load((const f32x4*)(gsrc + (T)*64)); \
                       sg1b = __builtin_nontemporal_load((const f32x4*)(gsrc + (T)*64 + 4)); }
#define LOAD_SET2(T) { sg2a = __builtin_nontemporal_load((const f32x4*)(gsrc + (T)*64)); \
                       sg2b = __builtin_nontemporal_load((const f32x4*)(gsrc + (T)*64 + 4)); }
#define CVT_SET(A, Bv, BUF) { s16x8 hb_; \
    hb_[0] = (short)f2bf((A)[0]); hb_[1] = (short)f2bf((A)[1]); \
    hb_[2] = (short)f2bf((A)[2]); hb_[3] = (short)f2bf((A)[3]); \
    hb_[4] = (short)f2bf((Bv)[0]); hb_[5] = (short)f2bf((Bv)[1]); \
    hb_[6] = (short)f2bf((Bv)[2]); hb_[7] = (short)f2bf((Bv)[3]); \
    *(s16x8*)(&bt[BUF][sbyte]) = hb_; }

  // prologue: tiles 0,1,2 in flight; tile 0 written to bt[0]
  LOAD_SET0(0);
  LOAD_SET1(1);
  LOAD_SET2(2);
  CVT_SET(sg0a, sg0b, 0);
  asm volatile("s_waitcnt lgkmcnt(0)" ::: "memory");
  __builtin_amdgcn_s_barrier();
  __builtin_amdgcn_sched_barrier(0);

#pragma unroll
  for (int t = 0; t < 8; ++t) {
    const char* cur = bt[t & 1];
    // (1) ds_reads for both kk halves first
    s16x8 bfrag[2][4];
#pragma unroll
    for (int kk = 0; kk < 2; ++kk)
#pragma unroll
      for (int n = 0; n < 4; ++n) {
        const int sr = n * 16 + bln;
        const int off = (kk * 64 + blh * 16) ^ ((sr & 7) << 4);
        bfrag[kk][n] = *(const s16x8*)(cur + sr * 128 + off);
      }
    // (2) A-frag loads (8 contiguous 1KB bursts from L2)
    s16x8 af[2][4];
#pragma unroll
    for (int kk = 0; kk < 2; ++kk)
#pragma unroll
      for (int m = 0; m < 4; ++m)
        af[kk][m] = *(const s16x8*)(ap + (size_t)(t * 2 + kk) * 32 * 512 +
                                    (size_t)m * 512);
    // (3) stage-load tile t+3 into set (t+3)%3
    if (t < 5) {
      const int s3 = (t + 3) % 3;
      if (s3 == 0) LOAD_SET0(t + 3)
      else if (s3 == 1) LOAD_SET1(t + 3)
      else LOAD_SET2(t + 3)
    }
    // (4) all 32 MFMAs, priority-boosted
    __builtin_amdgcn_s_setprio(1);
#pragma unroll
    for (int kk = 0; kk < 2; ++kk)
#pragma unroll
      for (int m = 0; m < 4; ++m)
#pragma unroll
        for (int n = 0; n < 4; ++n)
          acc[m][n] = __builtin_amdgcn_mfma_f32_16x16x32_bf16(af[kk][m],
                                                              bfrag[kk][n],
                                                              acc[m][n], 0, 0, 0);
    __builtin_amdgcn_s_setprio(0);
    // (5) write tile t+1 (loaded at iter t-2)
    if (t < 7) {
      const int s1 = (t + 1) % 3;
      const int nb = (t + 1) & 1;
      if (s1 == 0) CVT_SET(sg0a, sg0b, nb)
      else if (s1 == 1) CVT_SET(sg1a, sg1b, nb)
      else CVT_SET(sg2a, sg2b, nb)
    }
    // (6) barrier WITHOUT vmcnt drain
    asm volatile("s_waitcnt lgkmcnt(0)" ::: "memory");
    __builtin_amdgcn_s_barrier();
    __builtin_amdgcn_sched_barrier(0);
  }
#undef LOAD_SET0
#undef LOAD_SET1
#undef LOAD_SET2
#undef CVT_SET

  // epilogue: tanh + V-dot, reduce over h
  float attp[4] = {0.f, 0.f, 0.f, 0.f};
  const float* ib = inp_pb + b * H_;
#pragma unroll
  for (int m = 0; m < 4; ++m) {
#pragma unroll
    for (int j = 0; j < 4; ++j) {
      int h = hbase + m * 16 + (blh << 2) + j;
      float c = ib[h];
      float vh = V[h];
#pragma unroll
      for (int n = 0; n < 4; ++n) {
        float x = acc[m][n][j] + c;
        float e = __expf(2.f * x);
        float tt = 1.f - 2.f * __builtin_amdgcn_rcpf(e + 1.f);
        attp[n] += vh * tt;
      }
    }
  }
#pragma unroll
  for (int n = 0; n < 4; ++n) {
    attp[n] += __shfl_xor(attp[n], 16, 64);
    attp[n] += __shfl_xor(attp[n], 32, 64);
  }
  if (lane < 16) {
#pragma unroll
    for (int n = 0; n < 4; ++n) red[wave][n * 16 + lane] = attp[n];
  }
  __syncthreads();
  if (tid < 64) {
    float s = 0.f;
#pragma unroll
    for (int w = 0; w < 8; ++w) s += red[w][tid];
    att[(size_t)b * S_ + s0 + tid] = s;
  }

  // ---- fused masked softmax: the 32nd (last) WG of this b does the full row
  __shared__ int lastflag;
  __shared__ int cshared;
  __shared__ float sm[8];
  __syncthreads();  // att stores drained (vmcnt0 at barrier)
  if (tid == 0) {
    __threadfence();  // release att tile (device scope)
    int old = atomicAdd(&done[b], 1);
    lastflag = (old == 31);
  }
  __syncthreads();
  if (!lastflag) return;
  __threadfence();  // acquire all 32 att tiles

  if (tid < 64) {
    int v = flags[tid] | flags[tid + 64];
    for (int off = 32; off; off >>= 1) v |= __shfl_xor(v, off, 64);
    if (tid == 0) cshared = v;
  }
  __syncthreads();
  const int c = cshared;
  const int mtype = (c & 2) ? 2 : (c & 1);  // 2=float, 1=bytes, 0=int32
  const unsigned char* m8 = (const unsigned char*)mask;
  const int* m32 = (const int*)mask;
  const float* mf = (const float*)mask;
  float vals[4];
  float mx = -3.0e38f;
#pragma unroll
  for (int i = 0; i < 4; ++i) {
    int s = tid + i * 512;
    size_t idx = (size_t)b * S_ + s;
    int msk = (mtype == 1) ? (int)m8[idx] : (mtype == 2) ? (mf[idx] != 0.f) : m32[idx];
    float v = msk ? -__builtin_inff() : att[idx];
    vals[i] = v;
    mx = fmaxf(mx, v);
  }
  for (int off = 32; off; off >>= 1) mx = fmaxf(mx, __shfl_xor(mx, off, 64));
  if (lane == 0) sm[wave] = mx;
  __syncthreads();
  mx = sm[0];
#pragma unroll
  for (int w = 1; w < 8; ++w) mx = fmaxf(mx, sm[w]);
  float es[4];
  float sum = 0.f;
#pragma unroll
  for (int i = 0; i < 4; ++i) {
    es[i] = __expf(vals[i] - mx);
    sum += es[i];
  }
  for (int off = 32; off; off >>= 1) sum += __shfl_xor(sum, off, 64);
  __syncthreads();
  if (lane == 0) sm[wave] = sum;
  __syncthreads();
  sum = 0.f;
#pragma unroll
  for (int w = 0; w < 8; ++w) sum += sm[w];
  float inv = __fdividef(1.f, sum);
#pragma unroll
  for (int i = 0; i < 4; ++i)
    alpha[(size_t)b * S_ + tid + i * 512] = es[i] * inv;
}

// ---------------- y partials + FUSED hidden (last WG of each b) ----------------
// Reverse-order context read kept from R18 (neutral, harmless). After the
// chunk's y_part store: release + atomicAdd(done2[b]); 8th arriver sums the
// chunks and computes hidden[b,:] (W_ctx is L3-hot).
__global__ __launch_bounds__(256) void k_ypart(
    const float* __restrict__ context, const float* __restrict__ alpha,
    float* __restrict__ y_part, const float* __restrict__ W_ctx,
    const float* __restrict__ b_ctx, float* __restrict__ hidden,
    int* __restrict__ done2) {
  const int chunk = 7 - blockIdx.x, b = 63 - blockIdx.y, t = threadIdx.x;
  __shared__ float al[256];
  __shared__ float4 part[128];
  al[t] = alpha[(size_t)b * S_ + chunk * 256 + t];
  __syncthreads();
  const int d4 = t & 127, sr = t >> 7;
  const float4* base = (const float4*)(context + ((size_t)b * S_ + chunk * 256) * D_);
  float4 acc = make_float4(0.f, 0.f, 0.f, 0.f);
  for (int i = 0; i < 128; ++i) {
    int s = sr + 2 * i;
    float4 v = base[(size_t)s * 128 + d4];
    float a = al[s];
    acc.x += a * v.x; acc.y += a * v.y; acc.z += a * v.z; acc.w += a * v.w;
  }
  if (sr == 1) part[d4] = acc;
  __syncthreads();
  if (sr == 0) {
    float4 o = part[d4];
    o.x += acc.x; o.y += acc.y; o.z += acc.z; o.w += acc.w;
    *(float4*)(y_part + ((size_t)(b * 8 + chunk)) * D_ + d4 * 4) = o;
  }

  // fused hidden
  __shared__ int lastflag;
  __syncthreads();  // y_part stores drained
  if (t == 0) {
    __threadfence();
    int old = atomicAdd(&done2[b], 1);
    lastflag = (old == 7);
  }
  __syncthreads();
  if (!lastflag) return;
  __threadfence();

  __shared__ float ys[D_];
  for (int d = t; d < D_; d += 256) {
    float s = 0.f;
#pragma unroll
    for (int c2 = 0; c2 < 8; ++c2) s += y_part[((size_t)(b * 8 + c2)) * D_ + d];
    ys[d] = s;
  }
  __syncthreads();
  for (int h = t; h < H_; h += 256) {
    const float4* wr = (const float4*)(W_ctx + (size_t)h * D_);
    float acc2 = 0.f;
#pragma unroll 4
    for (int d4b = 0; d4b < 128; ++d4b) {
      float4 w = wr[d4b];
      acc2 += w.x * ys[d4b * 4] + w.y * ys[d4b * 4 + 1] + w.z * ys[d4b * 4 + 2] +
              w.w * ys[d4b * 4 + 3];
    }
    hidden[b * H_ + h] = acc2 + b_ctx[h];
  }
}

extern "C" void kernel_launch(void* const* d_in, const int* in_sizes, int n_in,
                              void* d_out, int out_size, void* d_ws, size_t ws_size,
                              hipStream_t stream) {
  (void)in_sizes; (void)n_in; (void)out_size; (void)ws_size;
  const float* x = (const float*)d_in[0];
  const float* context = (const float*)d_in[1];
  const void* mask = d_in[2];
  const float* W_in = (const float*)d_in[3];
  const float* b_in = (const float*)d_in[4];
  const float* W_ctx = (const float*)d_in[5];
  const float* b_ctx = (const float*)d_in[6];
  const float* V = (const float*)d_in[7];

  float* out_hidden = (float*)d_out;           // [B,H]
  float* out_alpha = (float*)d_out + B_ * H_;  // [B,S]

  // workspace: inp_pb 128K | att 512K | y_part 1M | flags 512B | done 256B |
  // done2 256B | Wp 512K
  char* ws = (char*)d_ws;
  float* inp_pb = (float*)ws;                            // B*H f32
  float* att = (float*)(ws + 131072);                    // B*S f32
  float* y_part = (float*)(ws + 655360);                 // B*8*D f32
  int* flags = (int*)(ws + 1703936);                     // 128 ints
  int* done = (int*)(ws + 1704448);                      // 64 ints
  int* done2 = (int*)(ws + 1704704);                     // 64 ints
  unsigned short* Wp = (unsigned short*)(ws + 1704960);  // H*D bf16 packed

  k_prep<<<512, 256, 0, stream>>>((const unsigned int*)mask, flags, done, done2,
                                  W_ctx, Wp, x, W_in, b_in, b_ctx, inp_pb);
  k_att<<<dim3(S_ / 64, B_), 512, 0, stream>>>(context, Wp, inp_pb, V, att,
                                               mask, flags, done, out_alpha);
  k_ypart<<<dim3(8, B_), 256, 0, stream>>>(context, out_alpha, y_part, W_ctx,
                                           b_ctx, out_hidden, done2);
}

// Round 20
// 182.570 us; speedup vs baseline: 2.3975x; 2.3975x over previous
//
#include <hip/hip_runtime.h>
#include <hip/hip_bf16.h>
#include <cstdint>

#define B_ 64
#define S_ 2048
#define D_ 512
#define H_ 512

typedef short s16x8 __attribute__((ext_vector_type(8)));
typedef float f32x4 __attribute__((ext_vector_type(4)));

static __device__ __forceinline__ unsigned short f2bf(float f) {
  __bf16 h = (__bf16)f;
  return __builtin_bit_cast(unsigned short, h);
}

// ---------------- fused prep: detect (128) + W-pack (128) + inp (256 blk) ----
__global__ __launch_bounds__(256) void k_prep(
    const unsigned int* __restrict__ mw, int* __restrict__ flags,
    const float* __restrict__ W, unsigned short* __restrict__ Wp,
    const float* __restrict__ x, const float* __restrict__ W_in,
    const float* __restrict__ b_in, const float* __restrict__ b_ctx,
    float* __restrict__ inp_pb) {
  const int bx = blockIdx.x;
  const int t = threadIdx.x;
  if (bx < 128) {
    __shared__ int blk;
    if (t == 0) blk = 0;
    __syncthreads();
    unsigned w = mw[bx * 256 + t];
    int bits = 0;
    if (w == 0x3F800000u) bits = 2;
    else if (w > 1u) bits = 1;
    unsigned long long a1 = __ballot(bits & 1);
    unsigned long long a2 = __ballot(bits & 2);
    if ((t & 63) == 0) {
      int v = (a1 ? 1 : 0) | (a2 ? 2 : 0);
      if (v) atomicOr(&blk, v);
    }
    __syncthreads();
    if (t == 0) flags[bx] = blk;
  } else if (bx < 256) {
    // pack W_ctx -> fragment-major bf16:
    // Wp[((kb*32+hb)*64+lane)*8+e] = bf16(W[hb*16+(lane&15)][kb*32+(lane>>4)*8+e])
    const int tid = (bx - 128) * 256 + t;
    const int lane = tid & 63;
    const int hb = (tid >> 6) & 31;
    const int kb = tid >> 11;
    const int h = hb * 16 + (lane & 15);
    const int k = kb * 32 + (lane >> 4) * 8;
    const float* src = W + (size_t)h * D_ + k;
    float4 a = *(const float4*)src;
    float4 c = *(const float4*)(src + 4);
    s16x8 o;
    o[0] = (short)f2bf(a.x); o[1] = (short)f2bf(a.y);
    o[2] = (short)f2bf(a.z); o[3] = (short)f2bf(a.w);
    o[4] = (short)f2bf(c.x); o[5] = (short)f2bf(c.y);
    o[6] = (short)f2bf(c.z); o[7] = (short)f2bf(c.w);
    *(s16x8*)(Wp + (size_t)tid * 8) = o;
  } else {
    // inp' = x @ W_in^T + b_in + b_ctx : 256 blocks = (b, h-quarter)
    const int bb = bx - 256;
    const int b = bb >> 2, hq = bb & 3;
    __shared__ float xs[D_];
    xs[t] = x[b * D_ + t];
    xs[t + 256] = x[b * D_ + t + 256];
    __syncthreads();
    const int h = hq * 128 + (t >> 1);
    const int half = t & 1;
    const float4* wr = (const float4*)(W_in + (size_t)h * D_) + half * 64;
    const float* xh = xs + half * 256;
    float acc = 0.f;
#pragma unroll 4
    for (int d4 = 0; d4 < 64; ++d4) {
      float4 w = wr[d4];
      acc += w.x * xh[d4 * 4] + w.y * xh[d4 * 4 + 1] + w.z * xh[d4 * 4 + 2] +
             w.w * xh[d4 * 4 + 3];
    }
    acc += __shfl_xor(acc, 1, 64);
    if (half == 0) inp_pb[b * H_ + h] = acc + b_in[h] + b_ctx[h];
  }
}

// ---------------- att[b,s] = sum_h V[h]*tanh(inp'[b,h] + (W_ctx@ctx^T)[h,s]) ----
// R13 schedule (measured best): depth-3 B staging, ds->A->stage->MFMA order,
// lgkm-only barriers, 0-conflict swizzle, setprio, cheap limit-exact tanh.
__global__ __launch_bounds__(512, 2) void k_att(
    const float* __restrict__ context, const unsigned short* __restrict__ Wp,
    const float* __restrict__ inp_pb, const float* __restrict__ V,
    float* __restrict__ att) {
  __shared__ char bt[2][8192];  // [s 64][k 64] bf16, 128B rows, swizzled
  __shared__ float red[8][64];
  const int tid = threadIdx.x;
  const int wave = tid >> 6, lane = tid & 63;
  const int b = blockIdx.y, s0 = blockIdx.x * 64;
  const float* ctxb = context + ((size_t)b * S_ + s0) * D_;
  const int hbase = wave * 64;
  const int bln = lane & 15, blh = lane >> 4;

  const int srow = tid >> 3, kc8 = (tid & 7) * 8;
  const int sbyte = srow * 128 + ((kc8 * 2) ^ ((srow & 7) << 4));
  const float* gsrc = ctxb + (size_t)srow * D_ + kc8;

  const unsigned short* ap = Wp + ((size_t)(wave * 4) * 64 + lane) * 8;

  f32x4 acc[4][4];
#pragma unroll
  for (int m = 0; m < 4; ++m)
#pragma unroll
    for (int n = 0; n < 4; ++n) acc[m][n] = f32x4{0.f, 0.f, 0.f, 0.f};

  // depth-3 staging register sets: set i holds tile x with x%3 == i
  f32x4 sg0a, sg0b, sg1a, sg1b, sg2a, sg2b;
#define LOAD_SET0(T) { sg0a = __builtin_nontemporal_load((const f32x4*)(gsrc + (T)*64)); \
                       sg0b = __builtin_nontemporal_load((const f32x4*)(gsrc + (T)*64 + 4)); }
#define LOAD_SET1(T) { sg1a = __builtin_nontemporal_load((const f32x4*)(gsrc + (T)*64)); \
                       sg1b = __builtin_nontemporal_load((const f32x4*)(gsrc + (T)*64 + 4)); }
#define LOAD_SET2(T) { sg2a = __builtin_nontemporal_load((const f32x4*)(gsrc + (T)*64)); \
                       sg2b = __builtin_nontemporal_load((const f32x4*)(gsrc + (T)*64 + 4)); }
#define CVT_SET(A, Bv, BUF) { s16x8 hb_; \
    hb_[0] = (short)f2bf((A)[0]); hb_[1] = (short)f2bf((A)[1]); \
    hb_[2] = (short)f2bf((A)[2]); hb_[3] = (short)f2bf((A)[3]); \
    hb_[4] = (short)f2bf((Bv)[0]); hb_[5] = (short)f2bf((Bv)[1]); \
    hb_[6] = (short)f2bf((Bv)[2]); hb_[7] = (short)f2bf((Bv)[3]); \
    *(s16x8*)(&bt[BUF][sbyte]) = hb_; }

  // prologue: tiles 0,1,2 in flight; tile 0 written to bt[0]
  LOAD_SET0(0);
  LOAD_SET1(1);
  LOAD_SET2(2);
  CVT_SET(sg0a, sg0b, 0);
  asm volatile("s_waitcnt lgkmcnt(0)" ::: "memory");
  __builtin_amdgcn_s_barrier();
  __builtin_amdgcn_sched_barrier(0);

#pragma unroll
  for (int t = 0; t < 8; ++t) {
    const char* cur = bt[t & 1];
    // (1) ds_reads for both kk halves first (LDS latency starts ticking)
    s16x8 bfrag[2][4];
#pragma unroll
    for (int kk = 0; kk < 2; ++kk)
#pragma unroll
      for (int n = 0; n < 4; ++n) {
        const int sr = n * 16 + bln;
        const int off = (kk * 64 + blh * 16) ^ ((sr & 7) << 4);
        bfrag[kk][n] = *(const s16x8*)(cur + sr * 128 + off);
      }
    // (2) A-frag loads (8 contiguous 1KB bursts from L2; latency overlaps ds)
    s16x8 af[2][4];
#pragma unroll
    for (int kk = 0; kk < 2; ++kk)
#pragma unroll
      for (int m = 0; m < 4; ++m)
        af[kk][m] = *(const s16x8*)(ap + (size_t)(t * 2 + kk) * 32 * 512 +
                                    (size_t)m * 512);
    // (3) stage-load tile t+3 into set (t+3)%3 (in flight across barriers)
    if (t < 5) {
      const int s3 = (t + 3) % 3;
      if (s3 == 0) LOAD_SET0(t + 3)
      else if (s3 == 1) LOAD_SET1(t + 3)
      else LOAD_SET2(t + 3)
    }
    // (4) all 32 MFMAs, priority-boosted
    __builtin_amdgcn_s_setprio(1);
#pragma unroll
    for (int kk = 0; kk < 2; ++kk)
#pragma unroll
      for (int m = 0; m < 4; ++m)
#pragma unroll
        for (int n = 0; n < 4; ++n)
          acc[m][n] = __builtin_amdgcn_mfma_f32_16x16x32_bf16(af[kk][m],
                                                              bfrag[kk][n],
                                                              acc[m][n], 0, 0, 0);
    __builtin_amdgcn_s_setprio(0);
    // (5) write tile t+1 (loaded at iter t-2: ~2.7 iters of cover)
    if (t < 7) {
      const int s1 = (t + 1) % 3;
      const int nb = (t + 1) & 1;
      if (s1 == 0) CVT_SET(sg0a, sg0b, nb)
      else if (s1 == 1) CVT_SET(sg1a, sg1b, nb)
      else CVT_SET(sg2a, sg2b, nb)
    }
    // (6) barrier WITHOUT vmcnt drain
    asm volatile("s_waitcnt lgkmcnt(0)" ::: "memory");
    __builtin_amdgcn_s_barrier();
    __builtin_amdgcn_sched_barrier(0);
  }
#undef LOAD_SET0
#undef LOAD_SET1
#undef LOAD_SET2
#undef CVT_SET

  // epilogue: tanh + V-dot, reduce over h
  float attp[4] = {0.f, 0.f, 0.f, 0.f};
  const float* ib = inp_pb + b * H_;
#pragma unroll
  for (int m = 0; m < 4; ++m) {
#pragma unroll
    for (int j = 0; j < 4; ++j) {
      int h = hbase + m * 16 + (blh << 2) + j;
      float c = ib[h];
      float vh = V[h];
#pragma unroll
      for (int n = 0; n < 4; ++n) {
        float x = acc[m][n][j] + c;
        float e = __expf(2.f * x);
        float tt = 1.f - 2.f * __builtin_amdgcn_rcpf(e + 1.f);
        attp[n] += vh * tt;
      }
    }
  }
#pragma unroll
  for (int n = 0; n < 4; ++n) {
    attp[n] += __shfl_xor(attp[n], 16, 64);
    attp[n] += __shfl_xor(attp[n], 32, 64);
  }
  if (lane < 16) {
#pragma unroll
    for (int n = 0; n < 4; ++n) red[wave][n * 16 + lane] = attp[n];
  }
  __syncthreads();
  if (tid < 64) {
    float s = 0.f;
#pragma unroll
    for (int w = 0; w < 8; ++w) s += red[w][tid];
    att[(size_t)b * S_ + s0 + tid] = s;
  }
}

// ---------------- masked softmax over S -> alpha ----------------
__global__ void k_softmax(const float* __restrict__ att, const void* __restrict__ mask,
                          const int* __restrict__ flags, float* __restrict__ alpha) {
  const int b = blockIdx.x, t = threadIdx.x;
  __shared__ int cshared;
  __shared__ float sm[4];
  if (t < 64) {
    int v = flags[t] | flags[t + 64];
    for (int off = 32; off; off >>= 1) v |= __shfl_xor(v, off, 64);
    if (t == 0) cshared = v;
  }
  __syncthreads();
  const int c = cshared;
  const int mtype = (c & 2) ? 2 : (c & 1);  // 2=float, 1=bytes, 0=int32
  const unsigned char* m8 = (const unsigned char*)mask;
  const int* m32 = (const int*)mask;
  const float* mf = (const float*)mask;
  float vals[8];
  float mx = -3.0e38f;
#pragma unroll
  for (int i = 0; i < 8; ++i) {
    int s = t + i * 256;
    size_t idx = (size_t)b * S_ + s;
    int msk = (mtype == 1) ? (int)m8[idx] : (mtype == 2) ? (mf[idx] != 0.f) : m32[idx];
    float v = msk ? -__builtin_inff() : att[idx];
    vals[i] = v;
    mx = fmaxf(mx, v);
  }
  for (int off = 32; off; off >>= 1) mx = fmaxf(mx, __shfl_xor(mx, off, 64));
  if ((t & 63) == 0) sm[t >> 6] = mx;
  __syncthreads();
  mx = fmaxf(fmaxf(sm[0], sm[1]), fmaxf(sm[2], sm[3]));
  float es[8];
  float sum = 0.f;
#pragma unroll
  for (int i = 0; i < 8; ++i) {
    es[i] = __expf(vals[i] - mx);
    sum += es[i];
  }
  for (int off = 32; off; off >>= 1) sum += __shfl_xor(sum, off, 64);
  __syncthreads();
  if ((t & 63) == 0) sm[t >> 6] = sum;
  __syncthreads();
  sum = sm[0] + sm[1] + sm[2] + sm[3];
  float inv = __fdividef(1.f, sum);
#pragma unroll
  for (int i = 0; i < 8; ++i) alpha[(size_t)b * S_ + t + i * 256] = es[i] * inv;
}

// ---------------- y partials: y[b,d] = sum_s alpha*context (f32) ----------------
// Reverse-order read kept (neutral, harmless).
__global__ void k_ypart(const float* __restrict__ context,
                        const float* __restrict__ alpha, float* __restrict__ y_part) {
  const int chunk = 7 - blockIdx.x, b = 63 - blockIdx.y, t = threadIdx.x;
  __shared__ float al[256];
  __shared__ float4 part[128];
  al[t] = alpha[(size_t)b * S_ + chunk * 256 + t];
  __syncthreads();
  const int d4 = t & 127, sr = t >> 7;
  const float4* base = (const float4*)(context + ((size_t)b * S_ + chunk * 256) * D_);
  float4 acc = make_float4(0.f, 0.f, 0.f, 0.f);
  for (int i = 0; i < 128; ++i) {
    int s = sr + 2 * i;
    float4 v = base[(size_t)s * 128 + d4];
    float a = al[s];
    acc.x += a * v.x; acc.y += a * v.y; acc.z += a * v.z; acc.w += a * v.w;
  }
  if (sr == 1) part[d4] = acc;
  __syncthreads();
  if (sr == 0) {
    float4 o = part[d4];
    o.x += acc.x; o.y += acc.y; o.z += acc.z; o.w += acc.w;
    *(float4*)(y_part + ((size_t)(b * 8 + chunk)) * D_ + d4 * 4) = o;
  }
}

// ---------------- hidden = W_ctx @ y + b_ctx : 256 blocks = (b, h-quarter) ----
__global__ __launch_bounds__(256) void k_hidden(
    const float* __restrict__ y_part, const float* __restrict__ W_ctx,
    const float* __restrict__ b_ctx, float* __restrict__ hidden) {
  const int bx = blockIdx.x;
  const int b = bx >> 2, hq = bx & 3;
  const int t = threadIdx.x;
  __shared__ float ys[D_];
  for (int d = t; d < D_; d += 256) {
    float s = 0.f;
#pragma unroll
    for (int c = 0; c < 8; ++c) s += y_part[((size_t)(b * 8 + c)) * D_ + d];
    ys[d] = s;
  }
  __syncthreads();
  const int h = hq * 128 + (t >> 1);
  const int half = t & 1;
  const float4* wr = (const float4*)(W_ctx + (size_t)h * D_) + half * 64;
  const float* yh = ys + half * 256;
  float acc = 0.f;
#pragma unroll 4
  for (int d4 = 0; d4 < 64; ++d4) {
    float4 w = wr[d4];
    acc += w.x * yh[d4 * 4] + w.y * yh[d4 * 4 + 1] + w.z * yh[d4 * 4 + 2] +
           w.w * yh[d4 * 4 + 3];
  }
  acc += __shfl_xor(acc, 1, 64);
  if (half == 0) hidden[b * H_ + h] = acc + b_ctx[h];
}

extern "C" void kernel_launch(void* const* d_in, const int* in_sizes, int n_in,
                              void* d_out, int out_size, void* d_ws, size_t ws_size,
                              hipStream_t stream) {
  (void)in_sizes; (void)n_in; (void)out_size; (void)ws_size;
  const float* x = (const float*)d_in[0];
  const float* context = (const float*)d_in[1];
  const void* mask = d_in[2];
  const float* W_in = (const float*)d_in[3];
  const float* b_in = (const float*)d_in[4];
  const float* W_ctx = (const float*)d_in[5];
  const float* b_ctx = (const float*)d_in[6];
  const float* V = (const float*)d_in[7];

  float* out_hidden = (float*)d_out;           // [B,H]
  float* out_alpha = (float*)d_out + B_ * H_;  // [B,S]

  // workspace: inp_pb 128K | att 512K | y_part 1M | flags 512B | Wp 512K
  char* ws = (char*)d_ws;
  float* inp_pb = (float*)ws;                            // B*H f32
  float* att = (float*)(ws + 131072);                    // B*S f32
  float* y_part = (float*)(ws + 655360);                 // B*8*D f32
  int* flags = (int*)(ws + 1703936);                     // 128 ints
  unsigned short* Wp = (unsigned short*)(ws + 1704448);  // H*D bf16 packed

  k_prep<<<512, 256, 0, stream>>>((const unsigned int*)mask, flags, W_ctx, Wp,
                                  x, W_in, b_in, b_ctx, inp_pb);
  k_att<<<dim3(S_ / 64, B_), 512, 0, stream>>>(context, Wp, inp_pb, V, att);
  k_softmax<<<B_, 256, 0, stream>>>(att, mask, flags, out_alpha);
  k_ypart<<<dim3(8, B_), 256, 0, stream>>>(context, out_alpha, y_part);
  k_hidden<<<256, 256, 0, stream>>>(y_part, W_ctx, b_ctx, out_hidden);
}